// Round 16
// baseline (75.352 us; speedup 1.0000x reference)
//
#include <hip/hip_runtime.h>
#include <hip/hip_bf16.h>

#define B_ 8
#define S_ 2048
#define DM 1024
#define DK 64

typedef __attribute__((ext_vector_type(8))) short bf16x8;
typedef __attribute__((ext_vector_type(4))) float f32x4;
typedef __attribute__((ext_vector_type(4))) short short4_t;
typedef unsigned int u32;

__device__ __forceinline__ short bf16s(float f) {
    union { float f; unsigned u; } v; v.f = f;
    unsigned r = v.u + 0x7fffu + ((v.u >> 16) & 1u);   // RNE
    return (short)(r >> 16);
}

__device__ __forceinline__ void gl_lds16(const void* g, void* l) {
    __builtin_amdgcn_global_load_lds(
        (const __attribute__((address_space(1))) u32*)g,
        (__attribute__((address_space(3))) u32*)l, 16, 0, 0);
}

// ---------------------------------------------------------------------------
// Kernel 0: convert W (3 x [64][1024] f32) -> bf16 in ws. 96 blocks x 256.
// ---------------------------------------------------------------------------
__global__ __launch_bounds__(256) void convw_kernel(
    const float* __restrict__ Wq, const float* __restrict__ Wk,
    const float* __restrict__ Wv, short* __restrict__ wbf)
{
    const int i = (blockIdx.x * 256 + threadIdx.x) * 8;
    const float* src = (i < 65536) ? Wq : (i < 131072) ? Wk : Wv;
    const int off = i & 65535;
    float4 f0 = *(const float4*)(src + off);
    float4 f1 = *(const float4*)(src + off + 4);
    bf16x8 o;
    o[0]=bf16s(f0.x); o[1]=bf16s(f0.y); o[2]=bf16s(f0.z); o[3]=bf16s(f0.w);
    o[4]=bf16s(f1.x); o[5]=bf16s(f1.y); o[6]=bf16s(f1.z); o[7]=bf16s(f1.w);
    *(bf16x8*)(wbf + i) = o;
}

// ---------------------------------------------------------------------------
// Kernel 1: fused QKV projection — M=128 tile (NEW axis): 128 rows/block,
// 384 blocks total. Same R15 inner structure: gl_lds staging, counted
// vmcnt(10) + raw s_barrier, XOR-swizzled via source. Wave owns 32 rows;
// W ds_reads amortized over 2 row-groups; W L2 re-reads halved.
// LDS: x [2][128r][256B] = 64 KB @0; W [2][64n][128B] = 16 KB @65536.
// ---------------------------------------------------------------------------
__global__ __launch_bounds__(256) void proj_kernel(
    const float* __restrict__ xq, const float* __restrict__ xk, const float* __restrict__ xv,
    const short* __restrict__ wbf,
    const float* __restrict__ bq, const float* __restrict__ bk, const float* __restrict__ bv,
    short* __restrict__ q_ws, short* __restrict__ k_ws, short* __restrict__ vt_ws)
{
    __shared__ __align__(16) char smem[81920];

    const int which = blockIdx.y;
    const float* x    = (which == 0) ? xq : (which == 1) ? xk : xv;
    const float* bias = (which == 0) ? bq : (which == 1) ? bk : bv;
    const short* wsrc = wbf + which * (DK * DM);

    const int tid = threadIdx.x;
    const int w   = tid >> 6;       // wave 0..3, owns rows w*32..w*32+31
    const int i   = tid & 63;
    const int lr  = i & 15;
    const int g   = i >> 4;
    const int row0 = blockIdx.x * 128;

    const int rot = (blockIdx.x * 5 + which * 7) & 15;

    f32x4 acc[2][4];
    #pragma unroll
    for (int h = 0; h < 2; ++h)
        #pragma unroll
        for (int f = 0; f < 4; ++f) acc[h][f] = f32x4{0.f, 0.f, 0.f, 0.f};

    // per chunk per wave: 8 x-insts (1 KB: rows j*4+(i>>4)) + 2 W-insts
    auto stage = [&](int buf, int kc) {
        char* xd = smem + buf * 32768 + (w * 32) * 256;
        const float* xrow = x + (long)(row0 + w * 32) * DM + kc;
        #pragma unroll
        for (int j = 0; j < 8; ++j) {
            const int rl  = j * 4 + (i >> 4);                  // row within wave's 32
            const int byt = ((i & 15) * 16) ^ ((rl & 7) << 5); // pre-swizzled source
            gl_lds16((const char*)(xrow + (long)rl * DM) + byt, xd + j * 1024);
        }
        char* wd = smem + 65536 + buf * 8192 + (w * 16) * 128;
        const short* wrow = wsrc + (long)(w * 16) * DM + kc;
        #pragma unroll
        for (int j = 0; j < 2; ++j) {
            const int nl  = j * 8 + (i >> 3);                  // n within wave's 16
            const int byt = ((i & 7) * 16) ^ ((nl & 7) << 4);
            gl_lds16((const char*)(wrow + (long)nl * DM) + byt, wd + j * 1024);
        }
    };

    auto compute = [&](int buf) {
        const char* wr = smem + 65536 + buf * 8192;
        const int sx = (lr & 7) << 5;
        const int sw = (lr & 7) << 4;
        #pragma unroll
        for (int ks = 0; ks < 2; ++ks) {
            // W fragments once per ks, reused by both row-groups
            bf16x8 wf[4];
            const int bB = (ks * 64 + g * 16) ^ sw;
            #pragma unroll
            for (int f = 0; f < 4; ++f)
                wf[f] = *(const bf16x8*)(wr + (f * 16 + lr) * 128 + bB);
            #pragma unroll
            for (int h = 0; h < 2; ++h) {
                const char* xr = smem + buf * 32768 + (w * 32 + h * 16 + lr) * 256;
                const int bA = (ks * 128 + g * 32) ^ sx;
                f32x4 x0 = *(const f32x4*)(xr + bA);
                f32x4 x1 = *(const f32x4*)(xr + bA + 16);
                bf16x8 af;
                af[0]=bf16s(x0[0]); af[1]=bf16s(x0[1]); af[2]=bf16s(x0[2]); af[3]=bf16s(x0[3]);
                af[4]=bf16s(x1[0]); af[5]=bf16s(x1[1]); af[6]=bf16s(x1[2]); af[7]=bf16s(x1[3]);
                #pragma unroll
                for (int f = 0; f < 4; ++f)
                    acc[h][f] = __builtin_amdgcn_mfma_f32_16x16x32_bf16(af, wf[f], acc[h][f], 0, 0, 0);
            }
        }
    };

    stage(0, rot * 64);
    __builtin_amdgcn_sched_barrier(0);
    stage(1, ((1 + rot) & 15) * 64);
    __builtin_amdgcn_sched_barrier(0);

    #pragma unroll 2
    for (int t = 0; t < 16; ++t) {
        if (t < 15) asm volatile("s_waitcnt vmcnt(10)" ::: "memory");
        else        asm volatile("s_waitcnt vmcnt(0)" ::: "memory");
        asm volatile("s_barrier" ::: "memory");
        const int buf = t & 1;
        compute(buf);
        asm volatile("s_waitcnt lgkmcnt(0)" ::: "memory");
        asm volatile("s_barrier" ::: "memory");
        if (t + 2 < 16) stage(buf, ((t + 2 + rot) & 15) * 64);
    }

    // ---- epilogue. D layout: lane reg r -> row = g*4+r, col = f*16+lr ----
    if (which < 2) {
        short* outp = (which == 0) ? q_ws : k_ws;
        #pragma unroll
        for (int h = 0; h < 2; ++h) {
            short* stile = (short*)smem + (w * 2 + h) * 1024;   // 16 KB total, disjoint
            #pragma unroll
            for (int f = 0; f < 4; ++f) {
                float bb = bias[f * 16 + lr];
                #pragma unroll
                for (int r = 0; r < 4; ++r)
                    stile[(g * 4 + r) * 64 + f * 16 + lr] = bf16s(acc[h][f][r] + bb);
            }
        }
        asm volatile("s_waitcnt lgkmcnt(0)" ::: "memory");   // same-wave LDS visibility
        __builtin_amdgcn_sched_barrier(0);
        #pragma unroll
        for (int h = 0; h < 2; ++h) {
            const short* stile = (const short*)smem + (w * 2 + h) * 1024;
            const long gbase = (long)(row0 + w * 32 + h * 16) * 64;
            *(bf16x8*)(outp + gbase +       i * 8) = *(const bf16x8*)(&stile[i * 8]);
            *(bf16x8*)(outp + gbase + 512 + i * 8) = *(const bf16x8*)(&stile[512 + i * 8]);
        }
    } else {
        #pragma unroll
        for (int h = 0; h < 2; ++h) {
            const int rw = row0 + w * 32 + h * 16;
            const int b = rw >> 11;
            const int s = (rw & 2047) + g * 4;
            #pragma unroll
            for (int f = 0; f < 4; ++f) {
                float bb = bias[f * 16 + lr];
                short4_t st;
                st[0]=bf16s(acc[h][f][0]+bb); st[1]=bf16s(acc[h][f][1]+bb);
                st[2]=bf16s(acc[h][f][2]+bb); st[3]=bf16s(acc[h][f][3]+bb);
                *(short4_t*)(vt_ws + (long)(b * 64 + f * 16 + lr) * S_ + s) = st;
            }
        }
    }
}

// ---------------------------------------------------------------------------
// Kernel 2: causal flash attention — REGISTER-RESIDENT P (R15 proven).
// Permuted K A-fragment rows make lane (lr,g) hold keys kv+g*8..+7, so P is
// directly the PV B-fragment. 4-wave KV round-robin + LDS merge + CU-aware
// mapping. 1024 blocks x 256 thr.
// ---------------------------------------------------------------------------
__global__ __launch_bounds__(256) void attn_kernel(
    const short* __restrict__ q_ws, const short* __restrict__ k_ws,
    const short* __restrict__ vt_ws, float* __restrict__ out)
{
    __shared__ __align__(16) float accds[4][64][16];
    __shared__ __align__(16) float2 mlds[4][16];

    const int n = blockIdx.x;
    const int c = n & 255, s = n >> 8;
    const int u = c & 127, v = c >> 7;
    const int b  = v * 4 + s;
    const int qt = (s & 1) ? (127 - u) : u;
    const int qbase = qt * 16;
    const int kend  = qbase + 16;
    const int niter = (kend + 31) >> 5;

    const int tid  = threadIdx.x;
    const int wv   = tid >> 6;
    const int lane = tid & 63;
    const int lr = lane & 15, g = lane >> 4, lk = g * 8;
    const int q_glob = qbase + lr;

    const short* qp = q_ws + ((long)b * S_ + qbase + lr) * DK;
    const bf16x8 qb0 = *(const bf16x8*)(qp + lk);
    const bf16x8 qb1 = *(const bf16x8*)(qp + 32 + lk);
    const int kperm = ((lr >> 2) << 3) + (lr & 3);
    const short* kb = k_ws  + (long)b * S_ * DK;
    const short* vb = vt_ws + (long)b * DK * S_;

    float m = -INFINITY, l = 0.f;
    f32x4 acc[4];
    #pragma unroll
    for (int f = 0; f < 4; ++f) acc[f] = f32x4{0.f, 0.f, 0.f, 0.f};
    const float sc = 0.125f * 1.44269504088896340736f;

    for (int t = wv; t < niter; t += 4) {
        const int kv = t * 32;
        bf16x8 vf0 = *(const bf16x8*)(vb + (long)(lr)      * S_ + kv + lk);
        bf16x8 vf1 = *(const bf16x8*)(vb + (long)(16 + lr) * S_ + kv + lk);
        bf16x8 vf2 = *(const bf16x8*)(vb + (long)(32 + lr) * S_ + kv + lk);
        bf16x8 vf3 = *(const bf16x8*)(vb + (long)(48 + lr) * S_ + kv + lk);

        const short* kp0 = kb + (long)(kv + kperm) * DK;
        const short* kp1 = kp0 + 4 * DK;
        bf16x8 k00 = *(const bf16x8*)(kp0 + lk);
        bf16x8 k01 = *(const bf16x8*)(kp0 + 32 + lk);
        bf16x8 k10 = *(const bf16x8*)(kp1 + lk);
        bf16x8 k11 = *(const bf16x8*)(kp1 + 32 + lk);

        f32x4 s0 = f32x4{0.f,0.f,0.f,0.f};
        s0 = __builtin_amdgcn_mfma_f32_16x16x32_bf16(k00, qb0, s0, 0, 0, 0);
        s0 = __builtin_amdgcn_mfma_f32_16x16x32_bf16(k01, qb1, s0, 0, 0, 0);
        f32x4 s1 = f32x4{0.f,0.f,0.f,0.f};
        s1 = __builtin_amdgcn_mfma_f32_16x16x32_bf16(k10, qb0, s1, 0, 0, 0);
        s1 = __builtin_amdgcn_mfma_f32_16x16x32_bf16(k11, qb1, s1, 0, 0, 0);

        float pv[8];
        #pragma unroll
        for (int r = 0; r < 4; ++r) {
            const int key0 = kv + g * 8 + r;
            pv[r]     = (key0 <= q_glob) ? s0[r] * sc : -INFINITY;
            const int key1 = kv + g * 8 + 4 + r;
            pv[4 + r] = (key1 <= q_glob) ? s1[r] * sc : -INFINITY;
        }
        float tm = fmaxf(fmaxf(fmaxf(pv[0],pv[1]), fmaxf(pv[2],pv[3])),
                         fmaxf(fmaxf(pv[4],pv[5]), fmaxf(pv[6],pv[7])));
        tm = fmaxf(tm, __shfl_xor(tm, 16));
        tm = fmaxf(tm, __shfl_xor(tm, 32));
        const float mn  = fmaxf(m, tm);
        const float fac = exp2f(m - mn);
        float ps = 0.f;
        #pragma unroll
        for (int q = 0; q < 8; ++q) { pv[q] = exp2f(pv[q] - mn); ps += pv[q]; }
        l = l * fac + ps;
        m = mn;
        #pragma unroll
        for (int f = 0; f < 4; ++f)
            #pragma unroll
            for (int r = 0; r < 4; ++r) acc[f][r] *= fac;

        bf16x8 pf;
        #pragma unroll
        for (int q = 0; q < 8; ++q) pf[q] = bf16s(pv[q]);

        acc[0] = __builtin_amdgcn_mfma_f32_16x16x32_bf16(vf0, pf, acc[0], 0, 0, 0);
        acc[1] = __builtin_amdgcn_mfma_f32_16x16x32_bf16(vf1, pf, acc[1], 0, 0, 0);
        acc[2] = __builtin_amdgcn_mfma_f32_16x16x32_bf16(vf2, pf, acc[2], 0, 0, 0);
        acc[3] = __builtin_amdgcn_mfma_f32_16x16x32_bf16(vf3, pf, acc[3], 0, 0, 0);
    }

    l += __shfl_xor(l, 16);
    l += __shfl_xor(l, 32);

    #pragma unroll
    for (int f = 0; f < 4; ++f)
        *(f32x4*)(&accds[wv][lane][f * 4]) = acc[f];
    if (g == 0) mlds[wv][lr] = float2{m, l};
    __syncthreads();

    const float2 ml0 = mlds[0][lr], ml1 = mlds[1][lr],
                 ml2 = mlds[2][lr], ml3 = mlds[3][lr];
    const float M = fmaxf(fmaxf(ml0.x, ml1.x), fmaxf(ml2.x, ml3.x));
    const float w0 = exp2f(ml0.x - M), w1 = exp2f(ml1.x - M),
                w2 = exp2f(ml2.x - M), w3 = exp2f(ml3.x - M);
    const float L = w0*ml0.y + w1*ml1.y + w2*ml2.y + w3*ml3.y;
    f32x4 o = w0 * (*(const f32x4*)(&accds[0][lane][wv * 4]))
            + w1 * (*(const f32x4*)(&accds[1][lane][wv * 4]))
            + w2 * (*(const f32x4*)(&accds[2][lane][wv * 4]))
            + w3 * (*(const f32x4*)(&accds[3][lane][wv * 4]));
    const float inv = 1.0f / L;
    o[0]*=inv; o[1]*=inv; o[2]*=inv; o[3]*=inv;
    *(f32x4*)(out + ((long)b * S_ + qbase + lr) * DK + wv * 16 + g * 4) = o;
}

extern "C" void kernel_launch(void* const* d_in, const int* in_sizes, int n_in,
                              void* d_out, int out_size, void* d_ws, size_t ws_size,
                              hipStream_t stream) {
    const float* q_in = (const float*)d_in[0];
    const float* k_in = (const float*)d_in[1];
    const float* v_in = (const float*)d_in[2];
    const float* Wq   = (const float*)d_in[3];
    const float* bq   = (const float*)d_in[4];
    const float* Wk   = (const float*)d_in[5];
    const float* bk   = (const float*)d_in[6];
    const float* Wv   = (const float*)d_in[7];
    const float* bv   = (const float*)d_in[8];

    short* q_ws  = (short*)d_ws;
    short* k_ws  = q_ws + (size_t)B_ * S_ * DK;
    short* vt_ws = k_ws + (size_t)B_ * S_ * DK;
    short* wbf   = vt_ws + (size_t)B_ * S_ * DK;
    float* out   = (float*)d_out;

    convw_kernel<<<dim3(96), 256, 0, stream>>>(Wq, Wk, Wv, wbf);
    proj_kernel<<<dim3((B_ * S_) / 128, 3), 256, 0, stream>>>(
        q_in, k_in, v_in, wbf, bq, bk, bv, q_ws, k_ws, vt_ws);
    attn_kernel<<<dim3(B_ * 128), 256, 0, stream>>>(q_ws, k_ws, vt_ws, out);
}

// Round 17
// 74.347 us; speedup vs baseline: 1.0135x; 1.0135x over previous
//
#include <hip/hip_runtime.h>
#include <hip/hip_bf16.h>

#define B_ 8
#define S_ 2048
#define DM 1024
#define DK 64

typedef __attribute__((ext_vector_type(8))) short bf16x8;
typedef __attribute__((ext_vector_type(4))) float f32x4;
typedef __attribute__((ext_vector_type(4))) short short4_t;
typedef unsigned int u32;

__device__ __forceinline__ short bf16s(float f) {
    union { float f; unsigned u; } v; v.f = f;
    unsigned r = v.u + 0x7fffu + ((v.u >> 16) & 1u);   // RNE
    return (short)(r >> 16);
}

__device__ __forceinline__ void gl_lds16(const void* g, void* l) {
    __builtin_amdgcn_global_load_lds(
        (const __attribute__((address_space(1))) u32*)g,
        (__attribute__((address_space(3))) u32*)l, 16, 0, 0);
}

// ---------------------------------------------------------------------------
// Kernel 0: convert W (3 x [64][1024] f32) -> bf16 in ws. 96 blocks x 256.
// ---------------------------------------------------------------------------
__global__ __launch_bounds__(256) void convw_kernel(
    const float* __restrict__ Wq, const float* __restrict__ Wk,
    const float* __restrict__ Wv, short* __restrict__ wbf)
{
    const int i = (blockIdx.x * 256 + threadIdx.x) * 8;
    const float* src = (i < 65536) ? Wq : (i < 131072) ? Wk : Wv;
    const int off = i & 65535;
    float4 f0 = *(const float4*)(src + off);
    float4 f1 = *(const float4*)(src + off + 4);
    bf16x8 o;
    o[0]=bf16s(f0.x); o[1]=bf16s(f0.y); o[2]=bf16s(f0.z); o[3]=bf16s(f0.w);
    o[4]=bf16s(f1.x); o[5]=bf16s(f1.y); o[6]=bf16s(f1.z); o[7]=bf16s(f1.w);
    *(bf16x8*)(wbf + i) = o;
}

// ---------------------------------------------------------------------------
// Kernel 1: fused QKV projection — M=128, BK=32: W re-read traffic halved
// (48 MB device-wide) AND occupancy kept (40 KB LDS -> 4 blocks/CU,
// 16 waves). R15 sync skeleton: gl_lds, counted vmcnt(5), raw s_barrier,
// granule-XOR swizzle via pre-swizzled source. grid (128,3) x 256 thr.
// LDS: x [2][128r][128B] = 32 KB @0; W [2][64n][64B] = 8 KB @32768.
// ---------------------------------------------------------------------------
__global__ __launch_bounds__(256) void proj_kernel(
    const float* __restrict__ xq, const float* __restrict__ xk, const float* __restrict__ xv,
    const short* __restrict__ wbf,
    const float* __restrict__ bq, const float* __restrict__ bk, const float* __restrict__ bv,
    short* __restrict__ q_ws, short* __restrict__ k_ws, short* __restrict__ vt_ws)
{
    __shared__ __align__(16) char smem[40960];

    const int which = blockIdx.y;
    const float* x    = (which == 0) ? xq : (which == 1) ? xk : xv;
    const float* bias = (which == 0) ? bq : (which == 1) ? bk : bv;
    const short* wsrc = wbf + which * (DK * DM);

    const int tid = threadIdx.x;
    const int w   = tid >> 6;       // wave 0..3, owns rows w*32..w*32+31
    const int i   = tid & 63;
    const int lr  = i & 15;
    const int g   = i >> 4;
    const int row0 = blockIdx.x * 128;

    const int rot = (blockIdx.x * 5 + which * 7) & 31;

    f32x4 acc[2][4];
    #pragma unroll
    for (int h = 0; h < 2; ++h)
        #pragma unroll
        for (int f = 0; f < 4; ++f) acc[h][f] = f32x4{0.f, 0.f, 0.f, 0.f};

    // per chunk per wave: 4 x-insts (8 rows x 128B each) + 1 W-inst = 5 vmem
    auto stage = [&](int buf, int kc) {
        char* xd = smem + buf * 16384 + (w * 32) * 128;
        const float* xrow = x + (long)(row0 + w * 32) * DM + kc;
        #pragma unroll
        for (int j = 0; j < 4; ++j) {
            const int rl  = j * 8 + (i >> 3);                  // row within wave's 32
            const int byt = ((i & 7) * 16) ^ ((rl & 7) << 4);  // pre-swizzled source
            gl_lds16((const char*)(xrow + (long)rl * DM) + byt, xd + j * 1024);
        }
        char* wd = smem + 32768 + buf * 4096 + (w * 16) * 64;
        const int nl  = i >> 2;                                // n within wave's 16
        const int byt = ((i & 3) * 16) ^ ((nl & 3) << 4);
        gl_lds16((const char*)(wsrc + (long)(w * 16 + nl) * DM + kc) + byt, wd);
    };

    // one 16x16x32 MFMA k-step per chunk (BK=32), both row-halves
    auto compute = [&](int buf) {
        const char* wr = smem + 32768 + buf * 4096;
        bf16x8 wf[4];
        #pragma unroll
        for (int f = 0; f < 4; ++f) {
            const int rn = f * 16 + lr;
            wf[f] = *(const bf16x8*)(wr + rn * 64 + ((g * 16) ^ ((rn & 3) << 4)));
        }
        #pragma unroll
        for (int h = 0; h < 2; ++h) {
            const int rr = h * 16 + lr;                        // row within wave's 32
            const char* xr = smem + buf * 16384 + (w * 32 + rr) * 128;
            const int sx = (rr & 7) << 4;
            f32x4 x0 = *(const f32x4*)(xr + ((g * 32) ^ sx));
            f32x4 x1 = *(const f32x4*)(xr + ((g * 32 + 16) ^ sx));
            bf16x8 af;
            af[0]=bf16s(x0[0]); af[1]=bf16s(x0[1]); af[2]=bf16s(x0[2]); af[3]=bf16s(x0[3]);
            af[4]=bf16s(x1[0]); af[5]=bf16s(x1[1]); af[6]=bf16s(x1[2]); af[7]=bf16s(x1[3]);
            #pragma unroll
            for (int f = 0; f < 4; ++f)
                acc[h][f] = __builtin_amdgcn_mfma_f32_16x16x32_bf16(af, wf[f], acc[h][f], 0, 0, 0);
        }
    };

    auto kcof = [&](int t) { return ((t + rot) & 31) * 32; };

    stage(0, kcof(0));
    __builtin_amdgcn_sched_barrier(0);
    stage(1, kcof(1));
    __builtin_amdgcn_sched_barrier(0);

    #pragma unroll 2
    for (int t = 0; t < 32; ++t) {
        if (t < 31) asm volatile("s_waitcnt vmcnt(5)" ::: "memory");
        else        asm volatile("s_waitcnt vmcnt(0)" ::: "memory");
        asm volatile("s_barrier" ::: "memory");
        const int buf = t & 1;
        compute(buf);
        asm volatile("s_waitcnt lgkmcnt(0)" ::: "memory");
        asm volatile("s_barrier" ::: "memory");
        if (t + 2 < 32) stage(buf, kcof(t + 2));
    }

    // ---- epilogue (R16-proven M=128 form). D: reg r -> row g*4+r, col f*16+lr
    if (which < 2) {
        short* outp = (which == 0) ? q_ws : k_ws;
        #pragma unroll
        for (int h = 0; h < 2; ++h) {
            short* stile = (short*)smem + (w * 2 + h) * 1024;   // 16 KB, disjoint
            #pragma unroll
            for (int f = 0; f < 4; ++f) {
                float bb = bias[f * 16 + lr];
                #pragma unroll
                for (int r = 0; r < 4; ++r)
                    stile[(g * 4 + r) * 64 + f * 16 + lr] = bf16s(acc[h][f][r] + bb);
            }
        }
        asm volatile("s_waitcnt lgkmcnt(0)" ::: "memory");   // same-wave LDS visibility
        __builtin_amdgcn_sched_barrier(0);
        #pragma unroll
        for (int h = 0; h < 2; ++h) {
            const short* stile = (const short*)smem + (w * 2 + h) * 1024;
            const long gbase = (long)(row0 + w * 32 + h * 16) * 64;
            *(bf16x8*)(outp + gbase +       i * 8) = *(const bf16x8*)(&stile[i * 8]);
            *(bf16x8*)(outp + gbase + 512 + i * 8) = *(const bf16x8*)(&stile[512 + i * 8]);
        }
    } else {
        #pragma unroll
        for (int h = 0; h < 2; ++h) {
            const int rw = row0 + w * 32 + h * 16;
            const int b = rw >> 11;
            const int s = (rw & 2047) + g * 4;
            #pragma unroll
            for (int f = 0; f < 4; ++f) {
                float bb = bias[f * 16 + lr];
                short4_t st;
                st[0]=bf16s(acc[h][f][0]+bb); st[1]=bf16s(acc[h][f][1]+bb);
                st[2]=bf16s(acc[h][f][2]+bb); st[3]=bf16s(acc[h][f][3]+bb);
                *(short4_t*)(vt_ws + (long)(b * 64 + f * 16 + lr) * S_ + s) = st;
            }
        }
    }
}

// ---------------------------------------------------------------------------
// Kernel 2: causal flash attention — REGISTER-RESIDENT P (R15 proven,
// unchanged). Permuted K A-fragment rows make lane (lr,g) hold keys
// kv+g*8..+7, so P is directly the PV B-fragment. 1024 blocks x 256 thr.
// ---------------------------------------------------------------------------
__global__ __launch_bounds__(256) void attn_kernel(
    const short* __restrict__ q_ws, const short* __restrict__ k_ws,
    const short* __restrict__ vt_ws, float* __restrict__ out)
{
    __shared__ __align__(16) float accds[4][64][16];
    __shared__ __align__(16) float2 mlds[4][16];

    const int n = blockIdx.x;
    const int c = n & 255, s = n >> 8;
    const int u = c & 127, v = c >> 7;
    const int b  = v * 4 + s;
    const int qt = (s & 1) ? (127 - u) : u;
    const int qbase = qt * 16;
    const int kend  = qbase + 16;
    const int niter = (kend + 31) >> 5;

    const int tid  = threadIdx.x;
    const int wv   = tid >> 6;
    const int lane = tid & 63;
    const int lr = lane & 15, g = lane >> 4, lk = g * 8;
    const int q_glob = qbase + lr;

    const short* qp = q_ws + ((long)b * S_ + qbase + lr) * DK;
    const bf16x8 qb0 = *(const bf16x8*)(qp + lk);
    const bf16x8 qb1 = *(const bf16x8*)(qp + 32 + lk);
    const int kperm = ((lr >> 2) << 3) + (lr & 3);
    const short* kb = k_ws  + (long)b * S_ * DK;
    const short* vb = vt_ws + (long)b * DK * S_;

    float m = -INFINITY, l = 0.f;
    f32x4 acc[4];
    #pragma unroll
    for (int f = 0; f < 4; ++f) acc[f] = f32x4{0.f, 0.f, 0.f, 0.f};
    const float sc = 0.125f * 1.44269504088896340736f;

    for (int t = wv; t < niter; t += 4) {
        const int kv = t * 32;
        bf16x8 vf0 = *(const bf16x8*)(vb + (long)(lr)      * S_ + kv + lk);
        bf16x8 vf1 = *(const bf16x8*)(vb + (long)(16 + lr) * S_ + kv + lk);
        bf16x8 vf2 = *(const bf16x8*)(vb + (long)(32 + lr) * S_ + kv + lk);
        bf16x8 vf3 = *(const bf16x8*)(vb + (long)(48 + lr) * S_ + kv + lk);

        const short* kp0 = kb + (long)(kv + kperm) * DK;
        const short* kp1 = kp0 + 4 * DK;
        bf16x8 k00 = *(const bf16x8*)(kp0 + lk);
        bf16x8 k01 = *(const bf16x8*)(kp0 + 32 + lk);
        bf16x8 k10 = *(const bf16x8*)(kp1 + lk);
        bf16x8 k11 = *(const bf16x8*)(kp1 + 32 + lk);

        f32x4 s0 = f32x4{0.f,0.f,0.f,0.f};
        s0 = __builtin_amdgcn_mfma_f32_16x16x32_bf16(k00, qb0, s0, 0, 0, 0);
        s0 = __builtin_amdgcn_mfma_f32_16x16x32_bf16(k01, qb1, s0, 0, 0, 0);
        f32x4 s1 = f32x4{0.f,0.f,0.f,0.f};
        s1 = __builtin_amdgcn_mfma_f32_16x16x32_bf16(k10, qb0, s1, 0, 0, 0);
        s1 = __builtin_amdgcn_mfma_f32_16x16x32_bf16(k11, qb1, s1, 0, 0, 0);

        float pv[8];
        #pragma unroll
        for (int r = 0; r < 4; ++r) {
            const int key0 = kv + g * 8 + r;
            pv[r]     = (key0 <= q_glob) ? s0[r] * sc : -INFINITY;
            const int key1 = kv + g * 8 + 4 + r;
            pv[4 + r] = (key1 <= q_glob) ? s1[r] * sc : -INFINITY;
        }
        float tm = fmaxf(fmaxf(fmaxf(pv[0],pv[1]), fmaxf(pv[2],pv[3])),
                         fmaxf(fmaxf(pv[4],pv[5]), fmaxf(pv[6],pv[7])));
        tm = fmaxf(tm, __shfl_xor(tm, 16));
        tm = fmaxf(tm, __shfl_xor(tm, 32));
        const float mn  = fmaxf(m, tm);
        const float fac = exp2f(m - mn);
        float ps = 0.f;
        #pragma unroll
        for (int q = 0; q < 8; ++q) { pv[q] = exp2f(pv[q] - mn); ps += pv[q]; }
        l = l * fac + ps;
        m = mn;
        #pragma unroll
        for (int f = 0; f < 4; ++f)
            #pragma unroll
            for (int r = 0; r < 4; ++r) acc[f][r] *= fac;

        bf16x8 pf;
        #pragma unroll
        for (int q = 0; q < 8; ++q) pf[q] = bf16s(pv[q]);

        acc[0] = __builtin_amdgcn_mfma_f32_16x16x32_bf16(vf0, pf, acc[0], 0, 0, 0);
        acc[1] = __builtin_amdgcn_mfma_f32_16x16x32_bf16(vf1, pf, acc[1], 0, 0, 0);
        acc[2] = __builtin_amdgcn_mfma_f32_16x16x32_bf16(vf2, pf, acc[2], 0, 0, 0);
        acc[3] = __builtin_amdgcn_mfma_f32_16x16x32_bf16(vf3, pf, acc[3], 0, 0, 0);
    }

    l += __shfl_xor(l, 16);
    l += __shfl_xor(l, 32);

    #pragma unroll
    for (int f = 0; f < 4; ++f)
        *(f32x4*)(&accds[wv][lane][f * 4]) = acc[f];
    if (g == 0) mlds[wv][lr] = float2{m, l};
    __syncthreads();

    const float2 ml0 = mlds[0][lr], ml1 = mlds[1][lr],
                 ml2 = mlds[2][lr], ml3 = mlds[3][lr];
    const float M = fmaxf(fmaxf(ml0.x, ml1.x), fmaxf(ml2.x, ml3.x));
    const float w0 = exp2f(ml0.x - M), w1 = exp2f(ml1.x - M),
                w2 = exp2f(ml2.x - M), w3 = exp2f(ml3.x - M);
    const float L = w0*ml0.y + w1*ml1.y + w2*ml2.y + w3*ml3.y;
    f32x4 o = w0 * (*(const f32x4*)(&accds[0][lane][wv * 4]))
            + w1 * (*(const f32x4*)(&accds[1][lane][wv * 4]))
            + w2 * (*(const f32x4*)(&accds[2][lane][wv * 4]))
            + w3 * (*(const f32x4*)(&accds[3][lane][wv * 4]));
    const float inv = 1.0f / L;
    o[0]*=inv; o[1]*=inv; o[2]*=inv; o[3]*=inv;
    *(f32x4*)(out + ((long)b * S_ + qbase + lr) * DK + wv * 16 + g * 4) = o;
}

extern "C" void kernel_launch(void* const* d_in, const int* in_sizes, int n_in,
                              void* d_out, int out_size, void* d_ws, size_t ws_size,
                              hipStream_t stream) {
    const float* q_in = (const float*)d_in[0];
    const float* k_in = (const float*)d_in[1];
    const float* v_in = (const float*)d_in[2];
    const float* Wq   = (const float*)d_in[3];
    const float* bq   = (const float*)d_in[4];
    const float* Wk   = (const float*)d_in[5];
    const float* bk   = (const float*)d_in[6];
    const float* Wv   = (const float*)d_in[7];
    const float* bv   = (const float*)d_in[8];

    short* q_ws  = (short*)d_ws;
    short* k_ws  = q_ws + (size_t)B_ * S_ * DK;
    short* vt_ws = k_ws + (size_t)B_ * S_ * DK;
    short* wbf   = vt_ws + (size_t)B_ * S_ * DK;
    float* out   = (float*)d_out;

    convw_kernel<<<dim3(96), 256, 0, stream>>>(Wq, Wk, Wv, wbf);
    proj_kernel<<<dim3((B_ * S_) / 128, 3), 256, 0, stream>>>(
        q_in, k_in, v_in, wbf, bq, bk, bv, q_ws, k_ws, vt_ws);
    attn_kernel<<<dim3(B_ * 128), 256, 0, stream>>>(q_ws, k_ws, vt_ws, out);
}

// Round 18
// 71.987 us; speedup vs baseline: 1.0467x; 1.0328x over previous
//
#include <hip/hip_runtime.h>
#include <hip/hip_bf16.h>

#define B_ 8
#define S_ 2048
#define DM 1024
#define DK 64

typedef __attribute__((ext_vector_type(8))) short bf16x8;
typedef __attribute__((ext_vector_type(4))) float f32x4;
typedef __attribute__((ext_vector_type(4))) short short4_t;
typedef unsigned int u32;

__device__ __forceinline__ short bf16s(float f) {
    union { float f; unsigned u; } v; v.f = f;
    unsigned r = v.u + 0x7fffu + ((v.u >> 16) & 1u);   // RNE
    return (short)(r >> 16);
}

__device__ __forceinline__ void gl_lds16(const void* g, void* l) {
    __builtin_amdgcn_global_load_lds(
        (const __attribute__((address_space(1))) u32*)g,
        (__attribute__((address_space(3))) u32*)l, 16, 0, 0);
}

// ---------------------------------------------------------------------------
// Kernel 0: convert W (3 x [64][1024] f32) -> bf16 in ws. 96 blocks x 256.
// ---------------------------------------------------------------------------
__global__ __launch_bounds__(256) void convw_kernel(
    const float* __restrict__ Wq, const float* __restrict__ Wk,
    const float* __restrict__ Wv, short* __restrict__ wbf)
{
    const int i = (blockIdx.x * 256 + threadIdx.x) * 8;
    const float* src = (i < 65536) ? Wq : (i < 131072) ? Wk : Wv;
    const int off = i & 65535;
    float4 f0 = *(const float4*)(src + off);
    float4 f1 = *(const float4*)(src + off + 4);
    bf16x8 o;
    o[0]=bf16s(f0.x); o[1]=bf16s(f0.y); o[2]=bf16s(f0.z); o[3]=bf16s(f0.w);
    o[4]=bf16s(f1.x); o[5]=bf16s(f1.y); o[6]=bf16s(f1.z); o[7]=bf16s(f1.w);
    *(bf16x8*)(wbf + i) = o;
}

// ---------------------------------------------------------------------------
// Kernel 1: fused QKV projection — R15 champion (timed-best 72.2 us):
// M=64 tile, gl_lds staging (cached), counted vmcnt(6) + raw s_barrier,
// XOR-swizzled via pre-swizzled source. grid (256,3) x 256 thr.
// ---------------------------------------------------------------------------
__global__ __launch_bounds__(256) void proj_kernel(
    const float* __restrict__ xq, const float* __restrict__ xk, const float* __restrict__ xv,
    const short* __restrict__ wbf,
    const float* __restrict__ bq, const float* __restrict__ bk, const float* __restrict__ bv,
    short* __restrict__ q_ws, short* __restrict__ k_ws, short* __restrict__ vt_ws)
{
    __shared__ __align__(16) char smem[49152];

    const int which = blockIdx.y;
    const float* x    = (which == 0) ? xq : (which == 1) ? xk : xv;
    const float* bias = (which == 0) ? bq : (which == 1) ? bk : bv;
    const short* wsrc = wbf + which * (DK * DM);

    const int tid = threadIdx.x;
    const int w   = tid >> 6;
    const int i   = tid & 63;
    const int lr  = i & 15;
    const int g   = i >> 4;
    const int row0 = blockIdx.x * 64;

    const int rot = (blockIdx.x * 5 + which * 7) & 15;

    f32x4 acc[4];
    #pragma unroll
    for (int f = 0; f < 4; ++f) acc[f] = f32x4{0.f, 0.f, 0.f, 0.f};

    auto stage = [&](int buf, int kc) {
        char* xd = smem + buf * 16384 + (w * 16) * 256;
        const float* xrow = x + (long)(row0 + w * 16) * DM + kc;
        #pragma unroll
        for (int j = 0; j < 4; ++j) {
            const int rl  = j * 4 + (i >> 4);
            const int byt = ((i & 15) * 16) ^ ((rl & 7) << 5);
            gl_lds16((const char*)(xrow + (long)rl * DM) + byt, xd + j * 1024);
        }
        char* wd = smem + 32768 + buf * 8192 + (w * 16) * 128;
        const short* wrow = wsrc + (long)(w * 16) * DM + kc;
        #pragma unroll
        for (int j = 0; j < 2; ++j) {
            const int nl  = j * 8 + (i >> 3);
            const int byt = ((i & 7) * 16) ^ ((nl & 7) << 4);
            gl_lds16((const char*)(wrow + (long)nl * DM) + byt, wd + j * 1024);
        }
    };

    auto compute = [&](int buf) {
        const char* xr = smem + buf * 16384 + (w * 16 + lr) * 256;
        const char* wr = smem + 32768 + buf * 8192;
        const int sx = (lr & 7) << 5;
        const int sw = (lr & 7) << 4;
        #pragma unroll
        for (int ks = 0; ks < 2; ++ks) {
            const int bA = (ks * 128 + g * 32) ^ sx;
            f32x4 x0 = *(const f32x4*)(xr + bA);
            f32x4 x1 = *(const f32x4*)(xr + bA + 16);
            bf16x8 af;
            af[0]=bf16s(x0[0]); af[1]=bf16s(x0[1]); af[2]=bf16s(x0[2]); af[3]=bf16s(x0[3]);
            af[4]=bf16s(x1[0]); af[5]=bf16s(x1[1]); af[6]=bf16s(x1[2]); af[7]=bf16s(x1[3]);
            const int bB = (ks * 64 + g * 16) ^ sw;
            #pragma unroll
            for (int f = 0; f < 4; ++f) {
                bf16x8 wf = *(const bf16x8*)(wr + (f * 16 + lr) * 128 + bB);
                acc[f] = __builtin_amdgcn_mfma_f32_16x16x32_bf16(af, wf, acc[f], 0, 0, 0);
            }
        }
    };

    stage(0, rot * 64);
    __builtin_amdgcn_sched_barrier(0);
    stage(1, ((1 + rot) & 15) * 64);
    __builtin_amdgcn_sched_barrier(0);

    #pragma unroll 2
    for (int t = 0; t < 16; ++t) {
        if (t < 15) asm volatile("s_waitcnt vmcnt(6)" ::: "memory");
        else        asm volatile("s_waitcnt vmcnt(0)" ::: "memory");
        asm volatile("s_barrier" ::: "memory");
        const int buf = t & 1;
        compute(buf);
        asm volatile("s_waitcnt lgkmcnt(0)" ::: "memory");
        asm volatile("s_barrier" ::: "memory");
        if (t + 2 < 16) stage(buf, ((t + 2 + rot) & 15) * 64);
    }

    if (which < 2) {
        short* stile = (short*)smem + w * 1024;
        #pragma unroll
        for (int f = 0; f < 4; ++f) {
            float bb = bias[f * 16 + lr];
            #pragma unroll
            for (int r = 0; r < 4; ++r)
                stile[(g * 4 + r) * 64 + f * 16 + lr] = bf16s(acc[f][r] + bb);
        }
        asm volatile("s_waitcnt lgkmcnt(0)" ::: "memory");
        __builtin_amdgcn_sched_barrier(0);
        short* outp = (which == 0) ? q_ws : k_ws;
        const long gbase = (long)(row0 + w * 16) * 64;
        *(bf16x8*)(outp + gbase +       i * 8) = *(const bf16x8*)(&stile[i * 8]);
        *(bf16x8*)(outp + gbase + 512 + i * 8) = *(const bf16x8*)(&stile[512 + i * 8]);
    } else {
        const int rw = row0 + w * 16;
        const int b = rw >> 11;
        const int s = (rw & 2047) + g * 4;
        #pragma unroll
        for (int f = 0; f < 4; ++f) {
            float bb = bias[f * 16 + lr];
            short4_t st;
            st[0]=bf16s(acc[f][0]+bb); st[1]=bf16s(acc[f][1]+bb);
            st[2]=bf16s(acc[f][2]+bb); st[3]=bf16s(acc[f][3]+bb);
            *(short4_t*)(vt_ws + (long)(b * 64 + f * 16 + lr) * S_ + s) = st;
        }
    }
}

// ---------------------------------------------------------------------------
// Kernel 2: causal flash attention — REGISTER-RESIDENT P (R15 champion).
// Permuted K A-fragment rows make lane (lr,g) hold keys kv+g*8..+7, so P is
// directly the PV B-fragment. 4-wave KV round-robin + LDS merge + CU-aware
// mapping. 1024 blocks x 256 thr.
// ---------------------------------------------------------------------------
__global__ __launch_bounds__(256) void attn_kernel(
    const short* __restrict__ q_ws, const short* __restrict__ k_ws,
    const short* __restrict__ vt_ws, float* __restrict__ out)
{
    __shared__ __align__(16) float accds[4][64][16];
    __shared__ __align__(16) float2 mlds[4][16];

    const int n = blockIdx.x;
    const int c = n & 255, s = n >> 8;
    const int u = c & 127, v = c >> 7;
    const int b  = v * 4 + s;
    const int qt = (s & 1) ? (127 - u) : u;
    const int qbase = qt * 16;
    const int kend  = qbase + 16;
    const int niter = (kend + 31) >> 5;

    const int tid  = threadIdx.x;
    const int wv   = tid >> 6;
    const int lane = tid & 63;
    const int lr = lane & 15, g = lane >> 4, lk = g * 8;
    const int q_glob = qbase + lr;

    const short* qp = q_ws + ((long)b * S_ + qbase + lr) * DK;
    const bf16x8 qb0 = *(const bf16x8*)(qp + lk);
    const bf16x8 qb1 = *(const bf16x8*)(qp + 32 + lk);
    const int kperm = ((lr >> 2) << 3) + (lr & 3);
    const short* kb = k_ws  + (long)b * S_ * DK;
    const short* vb = vt_ws + (long)b * DK * S_;

    float m = -INFINITY, l = 0.f;
    f32x4 acc[4];
    #pragma unroll
    for (int f = 0; f < 4; ++f) acc[f] = f32x4{0.f, 0.f, 0.f, 0.f};
    const float sc = 0.125f * 1.44269504088896340736f;

    for (int t = wv; t < niter; t += 4) {
        const int kv = t * 32;
        bf16x8 vf0 = *(const bf16x8*)(vb + (long)(lr)      * S_ + kv + lk);
        bf16x8 vf1 = *(const bf16x8*)(vb + (long)(16 + lr) * S_ + kv + lk);
        bf16x8 vf2 = *(const bf16x8*)(vb + (long)(32 + lr) * S_ + kv + lk);
        bf16x8 vf3 = *(const bf16x8*)(vb + (long)(48 + lr) * S_ + kv + lk);

        const short* kp0 = kb + (long)(kv + kperm) * DK;
        const short* kp1 = kp0 + 4 * DK;
        bf16x8 k00 = *(const bf16x8*)(kp0 + lk);
        bf16x8 k01 = *(const bf16x8*)(kp0 + 32 + lk);
        bf16x8 k10 = *(const bf16x8*)(kp1 + lk);
        bf16x8 k11 = *(const bf16x8*)(kp1 + 32 + lk);

        f32x4 s0 = f32x4{0.f,0.f,0.f,0.f};
        s0 = __builtin_amdgcn_mfma_f32_16x16x32_bf16(k00, qb0, s0, 0, 0, 0);
        s0 = __builtin_amdgcn_mfma_f32_16x16x32_bf16(k01, qb1, s0, 0, 0, 0);
        f32x4 s1 = f32x4{0.f,0.f,0.f,0.f};
        s1 = __builtin_amdgcn_mfma_f32_16x16x32_bf16(k10, qb0, s1, 0, 0, 0);
        s1 = __builtin_amdgcn_mfma_f32_16x16x32_bf16(k11, qb1, s1, 0, 0, 0);

        float pv[8];
        #pragma unroll
        for (int r = 0; r < 4; ++r) {
            const int key0 = kv + g * 8 + r;
            pv[r]     = (key0 <= q_glob) ? s0[r] * sc : -INFINITY;
            const int key1 = kv + g * 8 + 4 + r;
            pv[4 + r] = (key1 <= q_glob) ? s1[r] * sc : -INFINITY;
        }
        float tm = fmaxf(fmaxf(fmaxf(pv[0],pv[1]), fmaxf(pv[2],pv[3])),
                         fmaxf(fmaxf(pv[4],pv[5]), fmaxf(pv[6],pv[7])));
        tm = fmaxf(tm, __shfl_xor(tm, 16));
        tm = fmaxf(tm, __shfl_xor(tm, 32));
        const float mn  = fmaxf(m, tm);
        const float fac = exp2f(m - mn);
        float ps = 0.f;
        #pragma unroll
        for (int q = 0; q < 8; ++q) { pv[q] = exp2f(pv[q] - mn); ps += pv[q]; }
        l = l * fac + ps;
        m = mn;
        #pragma unroll
        for (int f = 0; f < 4; ++f)
            #pragma unroll
            for (int r = 0; r < 4; ++r) acc[f][r] *= fac;

        bf16x8 pf;
        #pragma unroll
        for (int q = 0; q < 8; ++q) pf[q] = bf16s(pv[q]);

        acc[0] = __builtin_amdgcn_mfma_f32_16x16x32_bf16(vf0, pf, acc[0], 0, 0, 0);
        acc[1] = __builtin_amdgcn_mfma_f32_16x16x32_bf16(vf1, pf, acc[1], 0, 0, 0);
        acc[2] = __builtin_amdgcn_mfma_f32_16x16x32_bf16(vf2, pf, acc[2], 0, 0, 0);
        acc[3] = __builtin_amdgcn_mfma_f32_16x16x32_bf16(vf3, pf, acc[3], 0, 0, 0);
    }

    l += __shfl_xor(l, 16);
    l += __shfl_xor(l, 32);

    #pragma unroll
    for (int f = 0; f < 4; ++f)
        *(f32x4*)(&accds[wv][lane][f * 4]) = acc[f];
    if (g == 0) mlds[wv][lr] = float2{m, l};
    __syncthreads();

    const float2 ml0 = mlds[0][lr], ml1 = mlds[1][lr],
                 ml2 = mlds[2][lr], ml3 = mlds[3][lr];
    const float M = fmaxf(fmaxf(ml0.x, ml1.x), fmaxf(ml2.x, ml3.x));
    const float w0 = exp2f(ml0.x - M), w1 = exp2f(ml1.x - M),
                w2 = exp2f(ml2.x - M), w3 = exp2f(ml3.x - M);
    const float L = w0*ml0.y + w1*ml1.y + w2*ml2.y + w3*ml3.y;
    f32x4 o = w0 * (*(const f32x4*)(&accds[0][lane][wv * 4]))
            + w1 * (*(const f32x4*)(&accds[1][lane][wv * 4]))
            + w2 * (*(const f32x4*)(&accds[2][lane][wv * 4]))
            + w3 * (*(const f32x4*)(&accds[3][lane][wv * 4]));
    const float inv = 1.0f / L;
    o[0]*=inv; o[1]*=inv; o[2]*=inv; o[3]*=inv;
    *(f32x4*)(out + ((long)b * S_ + qbase + lr) * DK + wv * 16 + g * 4) = o;
}

extern "C" void kernel_launch(void* const* d_in, const int* in_sizes, int n_in,
                              void* d_out, int out_size, void* d_ws, size_t ws_size,
                              hipStream_t stream) {
    const float* q_in = (const float*)d_in[0];
    const float* k_in = (const float*)d_in[1];
    const float* v_in = (const float*)d_in[2];
    const float* Wq   = (const float*)d_in[3];
    const float* bq   = (const float*)d_in[4];
    const float* Wk   = (const float*)d_in[5];
    const float* bk   = (const float*)d_in[6];
    const float* Wv   = (const float*)d_in[7];
    const float* bv   = (const float*)d_in[8];

    short* q_ws  = (short*)d_ws;
    short* k_ws  = q_ws + (size_t)B_ * S_ * DK;
    short* vt_ws = k_ws + (size_t)B_ * S_ * DK;
    short* wbf   = vt_ws + (size_t)B_ * S_ * DK;
    float* out   = (float*)d_out;

    convw_kernel<<<dim3(96), 256, 0, stream>>>(Wq, Wk, Wv, wbf);
    proj_kernel<<<dim3((B_ * S_) / 64, 3), 256, 0, stream>>>(
        q_in, k_in, v_in, wbf, bq, bk, bv, q_ws, k_ws, vt_ws);
    attn_kernel<<<dim3(B_ * 128), 256, 0, stream>>>(q_ws, k_ws, vt_ws, out);
}